// Round 7
// baseline (46339.169 us; speedup 1.0000x reference)
//
#include <hip/hip_runtime.h>
#include <hip/hip_cooperative_groups.h>
#include <math.h>
#include <stdint.h>

namespace cg = cooperative_groups;

#define NBATCH 512
#define SLEN   128
#define HDIM   256

// ---------- R3 (fallback) scratch layout ----------
#define R3_WHE  0
#define R3_WHD  262144
#define R3_ME   524288
#define R3_MD   528384
#define R3_VE   532480
#define R3_VD   533504
#define R3_X0   534528
#define R3_WQG  535552      // WqgT [k][j] f32 (shared with coop path)
#define R3_WQP  601088
#define R3_WRGP 666624
#define R3_RG   797696      // refp_g [b][s][d] f32 (shared)
#define R3_RP   17574912    // refp_p (shared)
// ---------- coop-path extras (f64) ----------
#define C_H     34352128    // h f64 buf A [k=256][b=512]  262144 floats
#define C_WHE64 34614272    // Wh_enc f64 [r][k]           524288
#define C_WHD64 35138560    // Wh_dec f64                  524288
#define C_WRG64 35662848    // Wr_g f64 [d][k]             131072
#define C_WRP64 35793920    // Wr_p f64                    131072
#define C_ME64  35924992    // M_enc f64 [e][r]            8192
#define C_MD64  35933184    // M_dec f64                   8192
#define C_VE64  35941376    // f64 [r]                     2048
#define C_VD64  35943424    //                             2048
#define C_X064  35945472    //                             2048
#define C_LASTA 35947520    // int[512]                    512
#define C_H2    35948032    // h f64 buf B                 262144 floats
#define WS_FLOATS 36210176  // ~144.8 MB

__device__ __align__(16) float g_ws[WS_FLOATS];

__device__ __forceinline__ float sigf(float x) { return 1.0f / (1.0f + expf(-x)); }

__device__ __forceinline__ void tf2x32(uint32_t k0, uint32_t k1, uint32_t x0, uint32_t x1,
                                       uint32_t& o0, uint32_t& o1) {
    uint32_t ks2 = k0 ^ k1 ^ 0x1BD11BDAu;
    x0 += k0; x1 += k1;
#define RR(r) { x0 += x1; x1 = (x1 << r) | (x1 >> (32 - r)); x1 ^= x0; }
    RR(13) RR(15) RR(26) RR(6)   x0 += k1;  x1 += ks2 + 1u;
    RR(17) RR(29) RR(16) RR(24)  x0 += ks2; x1 += k0 + 2u;
    RR(13) RR(15) RR(26) RR(6)   x0 += k0;  x1 += k1 + 3u;
    RR(17) RR(29) RR(16) RR(24)  x0 += k1;  x1 += ks2 + 4u;
    RR(13) RR(15) RR(26) RR(6)   x0 += ks2; x1 += k0 + 5u;
#undef RR
    o0 = x0; o1 = x1;
}

// JAX partitionable-threefry: bits[n] = xor(threefry2x32(key,(0,n)))  [R3-verified exact]
__device__ __forceinline__ double gumbel_jax(uint32_t k0, uint32_t k1, uint32_t n) {
    uint32_t o0, o1; tf2x32(k0, k1, 0u, n, o0, o1);
    uint32_t bits = o0 ^ o1;
    float f = __uint_as_float((bits >> 9) | 0x3f800000u) - 1.0f;
    f = fmaxf(f, 1.17549435e-38f);
    return -log(-log((double)f));
}

// =============== pre-pack (both layouts) ===============
__global__ void pre_k(const float* __restrict__ embed_W, const float* __restrict__ embed_b,
                      const float* __restrict__ Wi_enc, const float* __restrict__ Wh_enc,
                      const float* __restrict__ b_enc,
                      const float* __restrict__ Wi_dec, const float* __restrict__ Wh_dec,
                      const float* __restrict__ b_dec, const float* __restrict__ dec0,
                      const float* __restrict__ Wq_g, const float* __restrict__ Wr_g,
                      const float* __restrict__ Wq_p, const float* __restrict__ Wr_p) {
    float* ws = g_ws;
    double* HA    = (double*)(ws + C_H);
    double* HB    = (double*)(ws + C_H2);
    double* WhE64 = (double*)(ws + C_WHE64);
    double* WhD64 = (double*)(ws + C_WHD64);
    double* WRG64 = (double*)(ws + C_WRG64);
    double* WRP64 = (double*)(ws + C_WRP64);
    double* ME64  = (double*)(ws + C_ME64);
    double* MD64  = (double*)(ws + C_MD64);
    double* VE64  = (double*)(ws + C_VE64);
    double* VD64  = (double*)(ws + C_VD64);
    double* X064  = (double*)(ws + C_X064);
    int* lastA    = (int*)(ws + C_LASTA);
    int i0 = blockIdx.x * blockDim.x + threadIdx.x;
    int np = gridDim.x * blockDim.x;
    for (int i = i0; i < 262144; i += np) {
        int g = i & 3, j = (i >> 2) & 255, k = i >> 10, r = (g << 8) + j;
        ws[R3_WHE + i] = Wh_enc[r * 256 + k];
        ws[R3_WHD + i] = Wh_dec[r * 256 + k];
        WhE64[i] = (double)Wh_enc[i];
        WhD64[i] = (double)Wh_dec[i];
    }
    for (int i = i0; i < 65536; i += np) {
        int j = i & 255, k = i >> 8;
        ws[R3_WQG + i] = Wq_g[j * 256 + k];
        ws[R3_WQP + i] = Wq_p[j * 256 + k];
        ws[R3_WRGP + 2 * i]     = Wr_g[j * 256 + k];
        ws[R3_WRGP + 2 * i + 1] = Wr_p[j * 256 + k];
        WRG64[i] = (double)Wr_g[i];
        WRP64[i] = (double)Wr_p[i];
    }
    for (int i = i0; i < 131072; i += np) { HA[i] = 0.0; HB[i] = 0.0; }
    for (int i = i0; i < 4096; i += np) {
        int g = i & 3, j = (i >> 2) & 255, k4 = i >> 10, r = (g << 8) + j;
        const float* we = embed_W + k4 * 256;
        const float* wa = Wi_enc + r * 256;
        const float* wb = Wi_dec + r * 256;
        double a = 0.0, bsum = 0.0;
        for (int E = 0; E < 256; ++E) { a += (double)we[E] * wa[E]; bsum += (double)we[E] * wb[E]; }
        ws[R3_ME + i] = (float)a; ws[R3_MD + i] = (float)bsum;
        // coop layout: [e][r]
        int e2 = i >> 10, r2 = i & 1023;
        const float* we2 = embed_W + e2 * 256;
        const float* wa2 = Wi_enc + r2 * 256;
        const float* wb2 = Wi_dec + r2 * 256;
        double a2 = 0.0, b2 = 0.0;
        for (int E = 0; E < 256; ++E) { a2 += (double)we2[E] * wa2[E]; b2 += (double)we2[E] * wb2[E]; }
        ME64[i] = a2; MD64[i] = b2;
    }
    for (int i = i0; i < 1024; i += np) {
        int g = i & 3, j = i >> 2, r = (g << 8) + j;
        const float* wa = Wi_enc + r * 256;
        const float* wb = Wi_dec + r * 256;
        double a = 0.0, bsum = 0.0, x = 0.0;
        for (int E = 0; E < 256; ++E) {
            a += (double)embed_b[E] * wa[E];
            bsum += (double)embed_b[E] * wb[E];
            x += (double)dec0[E] * wb[E];
        }
        ws[R3_VE + i] = (float)(a + (double)b_enc[r]);
        ws[R3_VD + i] = (float)(bsum + (double)b_dec[r]);
        ws[R3_X0 + i] = (float)(x + (double)b_dec[r]);
        // coop layout: flat r
        const float* wa2 = Wi_enc + i * 256;
        const float* wb2 = Wi_dec + i * 256;
        double a2 = 0.0, b2 = 0.0, x2 = 0.0;
        for (int E = 0; E < 256; ++E) {
            a2 += (double)embed_b[E] * wa2[E];
            b2 += (double)embed_b[E] * wb2[E];
            x2 += (double)dec0[E] * wb2[E];
        }
        VE64[i] = a2 + (double)b_enc[i];
        VD64[i] = b2 + (double)b_dec[i];
        X064[i] = x2 + (double)b_dec[i];
    }
    for (int i = i0; i < 512; i += np) lastA[i] = 0;
}

// =============== cooperative main (256 blocks x 1024 thr, ping-pong H) ===============
__global__ __launch_bounds__(1024, 4) void main_coop(
    const float* __restrict__ problems,
    const float* __restrict__ bq_g, const float* __restrict__ Vg,
    const float* __restrict__ bq_p, const float* __restrict__ Vp,
    const float* __restrict__ br_g, const float* __restrict__ br_p,
    float* __restrict__ out) {
    cg::grid_group gridg = cg::this_grid();
    float* ws = g_ws;
    double* Hrd = (double*)(ws + C_H);
    double* Hwr = (double*)(ws + C_H2);
    const double* WhE64 = (const double*)(ws + C_WHE64);
    const double* WhD64 = (const double*)(ws + C_WHD64);
    const double* WRG64 = (const double*)(ws + C_WRG64);
    const double* WRP64 = (const double*)(ws + C_WRP64);
    const double* ME64  = (const double*)(ws + C_ME64);
    const double* MD64  = (const double*)(ws + C_MD64);
    const double* VE64  = (const double*)(ws + C_VE64);
    const double* VD64  = (const double*)(ws + C_VD64);
    const double* X064  = (const double*)(ws + C_X064);
    int* lastA = (int*)(ws + C_LASTA);

    const int bid = blockIdx.x, tid = threadIdx.x;
    const int wave = tid >> 6, lane = tid & 63;
    // gate role
    const int bg = bid >> 5, jq = bid & 31;            // 8 batch groups x 32 col-octets
    const int g = wave & 3, cp = wave >> 2;            // 4 gates x 4 col-pairs
    const int bb = (bg << 6) + lane;
    const int jA = (jq << 3) + (cp << 1);
    const int rA = __builtin_amdgcn_readfirstlane((g << 8) + jA);
    const int rB = rA + 1;
    const bool isG = (wave < 8);
    const int dsel = __builtin_amdgcn_readfirstlane((jq << 3) + (wave & 7));
    const int jU = __builtin_amdgcn_readfirstlane((jq << 3) + wave);  // waves 0..7

    __shared__ double gbuf[4][8][64];
    __shared__ float hb[2][256];
    __shared__ float pA[2][2][256];
    __shared__ float pQ[2][2][256];
    __shared__ float pP[2][2][256];
    __shared__ float u_l[2][128];
    __shared__ float w_l[2][128];
    __shared__ unsigned char vis[2][128];

    double cc = 0.0;

    const float* prb = problems + (size_t)bb * SLEN * 4;
    const double* wAe = WhE64 + (size_t)rA * 256;
    const double* wBe = WhE64 + (size_t)rB * 256;
    const double* wre = (isG ? WRG64 : WRP64) + (size_t)dsel * 256;
    const double  brr = (double)(isG ? br_g[dsel] : br_p[dsel]);
    float* refsel = ws + (isG ? R3_RG : R3_RP) + (size_t)bb * (SLEN * HDIM) + dsel;

    // ---- encoder: iter t computes gates(t) from Hrd=h(t-1), writes h(t) to Hwr ----
    for (int t = 0; t <= SLEN; ++t) {
        double a0 = 0.0, a1 = 0.0, ar = brr;
        if (t < SLEN) {
            float4 p = *(const float4*)(prb + (t << 2));
            a0 = VE64[rA] + (double)p.x * ME64[rA] + (double)p.y * ME64[1024 + rA]
               + (double)p.z * ME64[2048 + rA] + (double)p.w * ME64[3072 + rA];
            a1 = VE64[rB] + (double)p.x * ME64[rB] + (double)p.y * ME64[1024 + rB]
               + (double)p.z * ME64[2048 + rB] + (double)p.w * ME64[3072 + rB];
        }
        if (t >= 1) {
            const double* hc = Hrd + bb;
#pragma unroll 8
            for (int k = 0; k < 256; ++k) {
                double h = hc[(size_t)k << 9];
                a0 += h * wAe[k];
                a1 += h * wBe[k];
                ar += h * wre[k];
            }
            refsel[(size_t)(t - 1) * 256] = (float)ar;
        }
        if (t < SLEN) {
            gbuf[g][(cp << 1) + 0][lane] = a0;
            gbuf[g][(cp << 1) + 1][lane] = a1;
        }
        __syncthreads();
        if (t < SLEN && wave < 8) {
            double g0 = gbuf[0][wave][lane], g1 = gbuf[1][wave][lane];
            double g2 = gbuf[2][wave][lane], g3 = gbuf[3][wave][lane];
            float ig = sigf((float)g0), fg = sigf((float)g1), ggt = tanhf((float)g2), og = sigf((float)g3);
            double cn = (double)fg * cc + (double)ig * (double)ggt;
            cc = cn;
            Hwr[(size_t)jU * 512 + bb] = (double)og * (double)tanhf((float)cn);
        }
        gridg.sync();
        if (t < SLEN) { double* tmp = Hrd; Hrd = Hwr; Hwr = tmp; }
    }
    // Hrd now holds encoder-final h

    // ---- decoder ----
    const double* wAd = WhD64 + (size_t)rA * 256;
    const double* wBd = WhD64 + (size_t)rB * 256;
    const int half = tid >> 9, stid = tid & 511;
    const int swave = stid >> 6;
    const int b = (bid << 1) + half;
    const float* refgb = ws + R3_RG + (size_t)b * (SLEN * HDIM);
    const float* refpb = ws + R3_RP + (size_t)b * (SLEN * HDIM);

    if (stid < 128) vis[half][stid] = 0;
    __syncthreads();

    for (int t = 0; t < SLEN; ++t) {
        // gate phase: read Hrd = h(t-1), write h(t) to Hwr
        double a0, a1;
        if (t == 0) {
            a0 = X064[rA]; a1 = X064[rB];
        } else {
            int ai = lastA[bb];
            float4 p = *(const float4*)(prb + (ai << 2));
            a0 = VD64[rA] + (double)p.x * MD64[rA] + (double)p.y * MD64[1024 + rA]
               + (double)p.z * MD64[2048 + rA] + (double)p.w * MD64[3072 + rA];
            a1 = VD64[rB] + (double)p.x * MD64[rB] + (double)p.y * MD64[1024 + rB]
               + (double)p.z * MD64[2048 + rB] + (double)p.w * MD64[3072 + rB];
        }
        {
            const double* hc = Hrd + bb;
#pragma unroll 8
            for (int k = 0; k < 256; ++k) {
                double h = hc[(size_t)k << 9];
                a0 += h * wAd[k];
                a1 += h * wBd[k];
            }
        }
        gbuf[g][(cp << 1) + 0][lane] = a0;
        gbuf[g][(cp << 1) + 1][lane] = a1;
        __syncthreads();
        if (wave < 8) {
            double g0 = gbuf[0][wave][lane], g1 = gbuf[1][wave][lane];
            double g2 = gbuf[2][wave][lane], g3 = gbuf[3][wave][lane];
            float ig = sigf((float)g0), fg = sigf((float)g1), ggt = tanhf((float)g2), og = sigf((float)g3);
            double cn = (double)fg * cc + (double)ig * (double)ggt;
            cc = cn;
            Hwr[(size_t)jU * 512 + bb] = (double)og * (double)tanhf((float)cn);
        }
        gridg.sync();

        // attention + sample: 2 batches/block (reads just-published Hwr)
        if (stid < 256) hb[half][stid] = (float)Hwr[(size_t)stid * 512 + b];
        __syncthreads();
        {   // qp_g partials
            int kh = stid >> 8, j = stid & 255, kbase = kh << 7;
            float qa = 0.f;
#pragma unroll 8
            for (int kk = 0; kk < 128; ++kk)
                qa = fmaf(hb[half][kbase + kk], ws[R3_WQG + ((kbase + kk) << 8) + j], qa);
            pA[half][kh][j] = qa;
        }
        __syncthreads();
        {   // glimpse u
            const int d0 = lane, d1 = lane + 64, d2 = lane + 128, d3 = lane + 192;
            const float q0 = pA[half][0][d0] + pA[half][1][d0] + bq_g[d0], vg0 = Vg[d0];
            const float q1 = pA[half][0][d1] + pA[half][1][d1] + bq_g[d1], vg1 = Vg[d1];
            const float q2 = pA[half][0][d2] + pA[half][1][d2] + bq_g[d2], vg2 = Vg[d2];
            const float q3 = pA[half][0][d3] + pA[half][1][d3] + bq_g[d3], vg3 = Vg[d3];
            for (int s = swave; s < SLEN; s += 8) {
                if (vis[half][s]) continue;
                const float* r0 = refgb + (s << 8);
                float part = tanhf(q0 + r0[d0]) * 10.f * vg0;
                part = fmaf(tanhf(q1 + r0[d1]) * 10.f, vg1, part);
                part = fmaf(tanhf(q2 + r0[d2]) * 10.f, vg2, part);
                part = fmaf(tanhf(q3 + r0[d3]) * 10.f, vg3, part);
                for (int off = 32; off; off >>= 1) part += __shfl_xor(part, off, 64);
                if (lane == 0) u_l[half][s] = part;
            }
        }
        __syncthreads();
        if (swave == 0) {   // glimpse softmax
            int s1 = lane, s2 = lane + 64;
            bool v1 = vis[half][s1], v2 = vis[half][s2];
            float m = fmaxf(v1 ? -1e30f : u_l[half][s1], v2 ? -1e30f : u_l[half][s2]);
            for (int off = 32; off; off >>= 1) m = fmaxf(m, __shfl_xor(m, off, 64));
            float e1 = v1 ? 0.f : expf(u_l[half][s1] - m);
            float e2 = v2 ? 0.f : expf(u_l[half][s2] - m);
            float den = e1 + e2;
            for (int off = 32; off; off >>= 1) den += __shfl_xor(den, off, 64);
            w_l[half][s1] = e1 / den;
            w_l[half][s2] = e2 / den;
        }
        __syncthreads();
        {   // q partials
            int kh = stid >> 8, j = stid & 255;
            float q = 0.f;
            int s0 = kh << 6;
            for (int s = s0; s < s0 + 64; ++s)
                if (!vis[half][s]) q = fmaf(w_l[half][s], refgb[(s << 8) + j], q);
            pQ[half][kh][j] = q;
        }
        __syncthreads();
        {   // qp_p partials
            int kh = stid >> 8, j = stid & 255, kbase = kh << 7;
            float qa = 0.f;
#pragma unroll 8
            for (int kk = 0; kk < 128; ++kk) {
                int k = kbase + kk;
                float qk = pQ[half][0][k] + pQ[half][1][k];
                qa = fmaf(qk, ws[R3_WQP + (k << 8) + j], qa);
            }
            pP[half][kh][j] = qa;
        }
        __syncthreads();
        {   // pointer logits
            const int d0 = lane, d1 = lane + 64, d2 = lane + 128, d3 = lane + 192;
            const float q0 = pP[half][0][d0] + pP[half][1][d0] + bq_p[d0], vp0 = Vp[d0];
            const float q1 = pP[half][0][d1] + pP[half][1][d1] + bq_p[d1], vp1 = Vp[d1];
            const float q2 = pP[half][0][d2] + pP[half][1][d2] + bq_p[d2], vp2 = Vp[d2];
            const float q3 = pP[half][0][d3] + pP[half][1][d3] + bq_p[d3], vp3 = Vp[d3];
            for (int s = swave; s < SLEN; s += 8) {
                if (vis[half][s]) continue;
                const float* r0 = refpb + (s << 8);
                float part = tanhf(q0 + r0[d0]) * 10.f * vp0;
                part = fmaf(tanhf(q1 + r0[d1]) * 10.f, vp1, part);
                part = fmaf(tanhf(q2 + r0[d2]) * 10.f, vp2, part);
                part = fmaf(tanhf(q3 + r0[d3]) * 10.f, vp3, part);
                for (int off = 32; off; off >>= 1) part += __shfl_xor(part, off, 64);
                if (lane == 0) u_l[half][s] = part;
            }
        }
        __syncthreads();
        if (swave == 0) {   // sample (jax-exact)
            int s1 = lane, s2 = lane + 64;
            bool v1 = vis[half][s1], v2 = vis[half][s2];
            float m = fmaxf(v1 ? -1e30f : u_l[half][s1], v2 ? -1e30f : u_l[half][s2]);
            for (int off = 32; off; off >>= 1) m = fmaxf(m, __shfl_xor(m, off, 64));
            float e1 = v1 ? 0.f : expf(u_l[half][s1] - m);
            float e2 = v2 ? 0.f : expf(u_l[half][s2] - m);
            float den = e1 + e2;
            for (int off = 32; off; off >>= 1) den += __shfl_xor(den, off, 64);
            uint32_t kk0, kk1;
            tf2x32(0u, 1u, 0u, (uint32_t)t, kk0, kk1);
            double z1 = v1 ? -1.0e300 : (double)u_l[half][s1] + gumbel_jax(kk0, kk1, (uint32_t)(b * 128 + s1));
            double z2 = v2 ? -1.0e300 : (double)u_l[half][s2] + gumbel_jax(kk0, kk1, (uint32_t)(b * 128 + s2));
            double bz; int bi;
            if (z2 > z1) { bz = z2; bi = s2; } else { bz = z1; bi = s1; }
            for (int off = 32; off; off >>= 1) {
                double oz = __shfl_xor(bz, off, 64);
                int oi = __shfl_xor(bi, off, 64);
                if (oz > bz || (oz == bz && oi < bi)) { bz = oz; bi = oi; }
            }
            if (lane == 0) {
                float pr = expf(u_l[half][bi] - m) / den;
                out[t * NBATCH + b] = pr;
                out[SLEN * NBATCH + t * NBATCH + b] = (float)bi;
                vis[half][bi] = 1;
                lastA[b] = bi;
            }
        }
        __syncthreads();
        gridg.sync();
        { double* tmp = Hrd; Hrd = Hwr; Hwr = tmp; }
    }
}

// =============== fallback: exact R3 kernel (proven pass @25.4ms) ===============
__global__ __launch_bounds__(512) void main_fb(
    const float* __restrict__ problems,
    const float* __restrict__ bq_g, const float* __restrict__ br_g, const float* __restrict__ V_g,
    const float* __restrict__ bq_p, const float* __restrict__ br_p, const float* __restrict__ V_p,
    float* __restrict__ out) {
    float* ws = g_ws;
    const int blk = blockIdx.x, tid = threadIdx.x;
    const int bb = tid >> 8, j = tid & 255, lane = tid & 63, wave = tid >> 6;
    const int b = (blk << 1) + bb;

    const float4* WhE = (const float4*)(ws + R3_WHE);
    const float4* WhD = (const float4*)(ws + R3_WHD);
    const float4* ME  = (const float4*)(ws + R3_ME);
    const float4* MD  = (const float4*)(ws + R3_MD);
    const float4* vE  = (const float4*)(ws + R3_VE);
    const float4* vD  = (const float4*)(ws + R3_VD);
    const float4* X0  = (const float4*)(ws + R3_X0);
    const float*  WqgT = ws + R3_WQG;
    const float*  WqpT = ws + R3_WQP;
    const float2* Wrgp = (const float2*)(ws + R3_WRGP);
    float* refg = ws + R3_RG + (size_t)b * SLEN * HDIM;
    float* refp = ws + R3_RP + (size_t)b * SLEN * HDIM;

    __shared__ double h_d[2][256];
    __shared__ double q_d[2][256];
    __shared__ double qp_d[2][256];
    __shared__ float u_l[2][128];
    __shared__ float w_l[2][128];
    __shared__ unsigned char vis[2][128];
    __shared__ int lastA[2];

    h_d[bb][j] = 0.0;
    if (j < 128) vis[bb][j] = 0;
    if (j == 0) lastA[bb] = 0;
    double c = 0.0;
    __syncthreads();

    const float* prb = problems + (size_t)b * SLEN * 4;

    for (int t = 0; t < SLEN; ++t) {
        float4 p = *(const float4*)(prb + (t << 2));
        float4 v = vE[j];
        float4 m0 = ME[j], m1 = ME[256 + j], m2 = ME[512 + j], m3 = ME[768 + j];
        double a0 = (double)v.x + (double)p.x * m0.x + (double)p.y * m1.x + (double)p.z * m2.x + (double)p.w * m3.x;
        double a1 = (double)v.y + (double)p.x * m0.y + (double)p.y * m1.y + (double)p.z * m2.y + (double)p.w * m3.y;
        double a2 = (double)v.z + (double)p.x * m0.z + (double)p.y * m1.z + (double)p.z * m2.z + (double)p.w * m3.z;
        double a3 = (double)v.w + (double)p.x * m0.w + (double)p.y * m1.w + (double)p.z * m2.w + (double)p.w * m3.w;
#pragma unroll 8
        for (int k = 0; k < 256; ++k) {
            double hk = h_d[bb][k]; float4 wv = WhE[(k << 8) + j];
            a0 += hk * (double)wv.x; a1 += hk * (double)wv.y;
            a2 += hk * (double)wv.z; a3 += hk * (double)wv.w;
        }
        float ig = sigf((float)a0), fg = sigf((float)a1), gg = tanhf((float)a2), og = sigf((float)a3);
        c = (double)fg * c + (double)ig * (double)gg;
        double hn = (double)og * (double)tanhf((float)c);
        __syncthreads();
        h_d[bb][j] = hn;
        __syncthreads();
        double rg = (double)br_g[j], rp_ = (double)br_p[j];
#pragma unroll 8
        for (int k = 0; k < 256; ++k) {
            double hk = h_d[bb][k]; float2 wr = Wrgp[(k << 8) + j];
            rg += hk * (double)wr.x; rp_ += hk * (double)wr.y;
        }
        refg[t * HDIM + j] = (float)rg;
        refp[t * HDIM + j] = (float)rp_;
    }

    for (int t = 0; t < SLEN; ++t) {
        double a0, a1, a2, a3;
        if (t == 0) {
            float4 v = X0[j]; a0 = v.x; a1 = v.y; a2 = v.z; a3 = v.w;
        } else {
            int a = lastA[bb];
            float4 p = *(const float4*)(prb + (a << 2));
            float4 v = vD[j];
            float4 m0 = MD[j], m1 = MD[256 + j], m2 = MD[512 + j], m3 = MD[768 + j];
            a0 = (double)v.x + (double)p.x * m0.x + (double)p.y * m1.x + (double)p.z * m2.x + (double)p.w * m3.x;
            a1 = (double)v.y + (double)p.x * m0.y + (double)p.y * m1.y + (double)p.z * m2.y + (double)p.w * m3.y;
            a2 = (double)v.z + (double)p.x * m0.z + (double)p.y * m1.z + (double)p.z * m2.z + (double)p.w * m3.z;
            a3 = (double)v.w + (double)p.x * m0.w + (double)p.y * m1.w + (double)p.z * m2.w + (double)p.w * m3.w;
        }
#pragma unroll 8
        for (int k = 0; k < 256; ++k) {
            double hk = h_d[bb][k]; float4 wv = WhD[(k << 8) + j];
            a0 += hk * (double)wv.x; a1 += hk * (double)wv.y;
            a2 += hk * (double)wv.z; a3 += hk * (double)wv.w;
        }
        float ig = sigf((float)a0), fg = sigf((float)a1), gg = tanhf((float)a2), og = sigf((float)a3);
        c = (double)fg * c + (double)ig * (double)gg;
        double hn = (double)og * (double)tanhf((float)c);
        __syncthreads();
        h_d[bb][j] = hn;
        __syncthreads();

        {
            double qa = (double)bq_g[j];
#pragma unroll 8
            for (int k = 0; k < 256; ++k) qa += h_d[bb][k] * (double)WqgT[(k << 8) + j];
            qp_d[bb][j] = qa;
        }
        __syncthreads();
        {
            int myb = wave >> 2;
            const float* rgb = ws + R3_RG + (size_t)((blk << 1) + myb) * SLEN * HDIM;
            for (int s = (wave & 3); s < SLEN; s += 4) {
                if (vis[myb][s]) continue;
                const float* r0 = rgb + s * HDIM;
                double part = 0.0;
#pragma unroll
                for (int dd = 0; dd < 4; ++dd) {
                    int d = lane + (dd << 6);
                    float arg = (float)(qp_d[myb][d] + (double)r0[d]);
                    part += (double)V_g[d] * (double)(tanhf(arg) * 10.0f);
                }
                for (int off = 32; off; off >>= 1) part += __shfl_xor(part, off, 64);
                if (lane == 0) u_l[myb][s] = (float)part;
            }
        }
        __syncthreads();
        if ((wave & 3) == 0) {
            int myb = wave >> 2;
            int s1 = lane, s2 = lane + 64;
            bool v1 = vis[myb][s1], v2 = vis[myb][s2];
            float m = fmaxf(v1 ? -1e30f : u_l[myb][s1], v2 ? -1e30f : u_l[myb][s2]);
            for (int off = 32; off; off >>= 1) m = fmaxf(m, __shfl_xor(m, off, 64));
            float e1 = v1 ? 0.f : expf(u_l[myb][s1] - m);
            float e2 = v2 ? 0.f : expf(u_l[myb][s2] - m);
            float den = e1 + e2;
            for (int off = 32; off; off >>= 1) den += __shfl_xor(den, off, 64);
            w_l[myb][s1] = e1 / den;
            w_l[myb][s2] = e2 / den;
        }
        __syncthreads();
        {
            double q = 0.0;
            for (int s = 0; s < SLEN; ++s)
                if (!vis[bb][s]) q += (double)w_l[bb][s] * (double)refg[s * HDIM + j];
            q_d[bb][j] = q;
        }
        __syncthreads();
        {
            double qa = (double)bq_p[j];
#pragma unroll 8
            for (int k = 0; k < 256; ++k) qa += q_d[bb][k] * (double)WqpT[(k << 8) + j];
            qp_d[bb][j] = qa;
        }
        __syncthreads();
        {
            int myb = wave >> 2;
            const float* rpb = ws + R3_RP + (size_t)((blk << 1) + myb) * SLEN * HDIM;
            for (int s = (wave & 3); s < SLEN; s += 4) {
                if (vis[myb][s]) continue;
                const float* r0 = rpb + s * HDIM;
                double part = 0.0;
#pragma unroll
                for (int dd = 0; dd < 4; ++dd) {
                    int d = lane + (dd << 6);
                    float arg = (float)(qp_d[myb][d] + (double)r0[d]);
                    part += (double)V_p[d] * (double)(tanhf(arg) * 10.0f);
                }
                for (int off = 32; off; off >>= 1) part += __shfl_xor(part, off, 64);
                if (lane == 0) u_l[myb][s] = (float)part;
            }
        }
        __syncthreads();
        if ((wave & 3) == 0) {
            int myb = wave >> 2;
            int gb = (blk << 1) + myb;
            int s1 = lane, s2 = lane + 64;
            bool v1 = vis[myb][s1], v2 = vis[myb][s2];
            float m = fmaxf(v1 ? -1e30f : u_l[myb][s1], v2 ? -1e30f : u_l[myb][s2]);
            for (int off = 32; off; off >>= 1) m = fmaxf(m, __shfl_xor(m, off, 64));
            float e1 = v1 ? 0.f : expf(u_l[myb][s1] - m);
            float e2 = v2 ? 0.f : expf(u_l[myb][s2] - m);
            float den = e1 + e2;
            for (int off = 32; off; off >>= 1) den += __shfl_xor(den, off, 64);
            uint32_t kk0, kk1;
            tf2x32(0u, 1u, 0u, (uint32_t)t, kk0, kk1);
            double z1 = v1 ? -1.0e300 : (double)u_l[myb][s1] + gumbel_jax(kk0, kk1, (uint32_t)(gb * 128 + s1));
            double z2 = v2 ? -1.0e300 : (double)u_l[myb][s2] + gumbel_jax(kk0, kk1, (uint32_t)(gb * 128 + s2));
            double bz; int bi;
            if (z2 > z1) { bz = z2; bi = s2; } else { bz = z1; bi = s1; }
            for (int off = 32; off; off >>= 1) {
                double oz = __shfl_xor(bz, off, 64);
                int oi = __shfl_xor(bi, off, 64);
                if (oz > bz || (oz == bz && oi < bi)) { bz = oz; bi = oi; }
            }
            if (lane == 0) {
                float pr = expf(u_l[myb][bi] - m) / den;
                out[t * NBATCH + gb] = pr;
                out[SLEN * NBATCH + t * NBATCH + gb] = (float)bi;
                vis[myb][bi] = 1;
                lastA[myb] = bi;
            }
        }
        __syncthreads();
    }
}

extern "C" void kernel_launch(void* const* d_in, const int* in_sizes, int n_in,
                              void* d_out, int out_size, void* d_ws, size_t ws_size,
                              hipStream_t stream) {
    (void)d_ws; (void)ws_size; (void)n_in; (void)in_sizes; (void)out_size;
    const float* problems = (const float*)d_in[0];
    const float* embed_W  = (const float*)d_in[1];
    const float* embed_b  = (const float*)d_in[2];
    const float* Wi_enc   = (const float*)d_in[3];
    const float* Wh_enc   = (const float*)d_in[4];
    const float* b_enc    = (const float*)d_in[5];
    const float* Wi_dec   = (const float*)d_in[6];
    const float* Wh_dec   = (const float*)d_in[7];
    const float* b_dec    = (const float*)d_in[8];
    const float* dec0     = (const float*)d_in[9];
    const float* Wq_g     = (const float*)d_in[10];
    const float* bq_g     = (const float*)d_in[11];
    const float* Wr_g     = (const float*)d_in[12];
    const float* br_g     = (const float*)d_in[13];
    const float* V_g      = (const float*)d_in[14];
    const float* Wq_p     = (const float*)d_in[15];
    const float* bq_p     = (const float*)d_in[16];
    const float* Wr_p     = (const float*)d_in[17];
    const float* br_p     = (const float*)d_in[18];
    const float* V_p      = (const float*)d_in[19];
    float* outp = (float*)d_out;

    hipLaunchKernelGGL(pre_k, dim3(512), dim3(256), 0, stream,
                       embed_W, embed_b, Wi_enc, Wh_enc, b_enc,
                       Wi_dec, Wh_dec, b_dec, dec0, Wq_g, Wr_g, Wq_p, Wr_p);

    void* args[] = { (void*)&problems, (void*)&bq_g, (void*)&V_g, (void*)&bq_p, (void*)&V_p,
                     (void*)&br_g, (void*)&br_p, (void*)&outp };
    hipError_t err = hipLaunchCooperativeKernel((void*)main_coop, dim3(256), dim3(1024),
                                                args, 0, stream);
    if (err != hipSuccess) {
        // fallback: proven R3 kernel (uses only R3_* arrays, also packed by pre_k)
        hipLaunchKernelGGL(main_fb, dim3(256), dim3(512), 0, stream,
                           problems, bq_g, br_g, V_g, bq_p, br_p, V_p, outp);
    }
}

// Round 8
// 20074.902 us; speedup vs baseline: 2.3083x; 2.3083x over previous
//
#include <hip/hip_runtime.h>
#include <math.h>
#include <stdint.h>

#define NB 512
#define SL 128

// float offsets into g_ws
#define O_WHE64   0           // Wh_enc f64 [r=1024][k=256]   524288 floats
#define O_WHD64   524288      // Wh_dec f64                   524288
#define O_ME64    1048576     // M_enc f64 [e=4][r=1024]      8192
#define O_MD64    1056768     // M_dec f64                    8192
#define O_VE64    1064960     // f64 [1024]                   2048
#define O_VD64    1067008     //                              2048
#define O_X064    1069056     //                              2048
#define O_WRT     1071104     // WrT f32 [k=256][col=512]     131072  (col<256: Wr_g, else Wr_p)
#define O_WQGT    1202176     // WqgT f32 [k][j]              65536
#define O_WQPT    1267712     //                              65536
#define O_HP0     1333248     // h f64 ping [k=256][b=512]    262144 floats
#define O_HP1     1595392     // h f64 pong                   262144
#define O_C64     1857536     // c f64 [k][b]                 262144
#define O_HCUR    2119680     // h f32 [b][k] (decoder)       131072
#define O_HALL    2250752     // enc h f32 [(b*128+t)][k]     16777216
#define O_RG      19027968    // refp_g f32 [(b*128+s)][d]    16777216
#define O_RP      35805184    // refp_p                       16777216
#define O_VIS     52582400    // int [b*128+s]                65536
#define O_LASTA   52647936    // int [512]                    512
#define WS_FLOATS 52648448    // ~210.6 MB

__device__ __align__(16) float g_ws[WS_FLOATS];

__device__ __forceinline__ float sigf(float x) { return 1.0f / (1.0f + expf(-x)); }

__device__ __forceinline__ void tf2x32(uint32_t k0, uint32_t k1, uint32_t x0, uint32_t x1,
                                       uint32_t& o0, uint32_t& o1) {
    uint32_t ks2 = k0 ^ k1 ^ 0x1BD11BDAu;
    x0 += k0; x1 += k1;
#define RR(r) { x0 += x1; x1 = (x1 << r) | (x1 >> (32 - r)); x1 ^= x0; }
    RR(13) RR(15) RR(26) RR(6)   x0 += k1;  x1 += ks2 + 1u;
    RR(17) RR(29) RR(16) RR(24)  x0 += ks2; x1 += k0 + 2u;
    RR(13) RR(15) RR(26) RR(6)   x0 += k0;  x1 += k1 + 3u;
    RR(17) RR(29) RR(16) RR(24)  x0 += k1;  x1 += ks2 + 4u;
    RR(13) RR(15) RR(26) RR(6)   x0 += ks2; x1 += k0 + 5u;
#undef RR
    o0 = x0; o1 = x1;
}

// JAX partitionable-threefry: bits[n] = xor(threefry2x32(key,(0,n)))  [R3-verified exact]
__device__ __forceinline__ double gumbel_jax(uint32_t k0, uint32_t k1, uint32_t n) {
    uint32_t o0, o1; tf2x32(k0, k1, 0u, n, o0, o1);
    uint32_t bits = o0 ^ o1;
    float f = __uint_as_float((bits >> 9) | 0x3f800000u) - 1.0f;
    f = fmaxf(f, 1.17549435e-38f);
    return -log(-log((double)f));
}

// =============== pre-pack ===============
__global__ void pre_k(const float* __restrict__ embed_W, const float* __restrict__ embed_b,
                      const float* __restrict__ Wi_enc, const float* __restrict__ Wh_enc,
                      const float* __restrict__ b_enc,
                      const float* __restrict__ Wi_dec, const float* __restrict__ Wh_dec,
                      const float* __restrict__ b_dec, const float* __restrict__ dec0,
                      const float* __restrict__ Wr_g, const float* __restrict__ Wr_p,
                      const float* __restrict__ Wq_g, const float* __restrict__ Wq_p) {
    float* ws = g_ws;
    double* WhE = (double*)(ws + O_WHE64);
    double* WhD = (double*)(ws + O_WHD64);
    double* ME  = (double*)(ws + O_ME64);
    double* MD  = (double*)(ws + O_MD64);
    double* VE  = (double*)(ws + O_VE64);
    double* VD  = (double*)(ws + O_VD64);
    double* X0  = (double*)(ws + O_X064);
    int* visG   = (int*)(ws + O_VIS);
    int* lastAG = (int*)(ws + O_LASTA);
    int i0 = blockIdx.x * blockDim.x + threadIdx.x;
    int np = gridDim.x * blockDim.x;
    for (int i = i0; i < 262144; i += np) {
        WhE[i] = (double)Wh_enc[i];
        WhD[i] = (double)Wh_dec[i];
    }
    for (int i = i0; i < 131072; i += np) {
        int k = i >> 9, col = i & 511;
        ws[O_WRT + i] = (col < 256) ? Wr_g[col * 256 + k] : Wr_p[(col - 256) * 256 + k];
    }
    for (int i = i0; i < 65536; i += np) {
        int j = i & 255, k = i >> 8;
        ws[O_WQGT + i] = Wq_g[j * 256 + k];
        ws[O_WQPT + i] = Wq_p[j * 256 + k];
    }
    for (int i = i0; i < 4096; i += np) {
        int e = i >> 10, r = i & 1023;
        const float* we = embed_W + e * 256;
        const float* wa = Wi_enc + r * 256;
        const float* wb = Wi_dec + r * 256;
        double a = 0.0, b = 0.0;
        for (int E = 0; E < 256; ++E) { a += (double)we[E] * wa[E]; b += (double)we[E] * wb[E]; }
        ME[i] = a; MD[i] = b;
    }
    for (int r = i0; r < 1024; r += np) {
        const float* wa = Wi_enc + r * 256;
        const float* wb = Wi_dec + r * 256;
        double a = 0.0, b = 0.0, x = 0.0;
        for (int E = 0; E < 256; ++E) {
            a += (double)embed_b[E] * wa[E];
            b += (double)embed_b[E] * wb[E];
            x += (double)dec0[E] * wb[E];
        }
        VE[r] = a + (double)b_enc[r];
        VD[r] = b + (double)b_dec[r];
        X0[r] = x + (double)b_dec[r];
    }
    for (int i = i0; i < 65536; i += np) visG[i] = 0;
    for (int i = i0; i < 512; i += np) lastAG[i] = 0;
}

// =============== encoder gate step ===============
// grid 512 x 256. block (bg=bid>>6 [8 batch groups x64], rg=bid&63 [64 col quads]).
// wave w computes gate g=w for cols rg*4..rg*4+3 over 64 batches (lanes).
__global__ __launch_bounds__(256) void gate_enc_k(const float* __restrict__ problems, int t) {
    float* ws = g_ws;
    const double* Wh = (const double*)(ws + O_WHE64);
    const double* M  = (const double*)(ws + O_ME64);
    const double* V  = (const double*)(ws + O_VE64);
    const double* Hrd = (const double*)(ws + ((t & 1) ? O_HP1 : O_HP0));
    double* Hwr = (double*)(ws + ((t & 1) ? O_HP0 : O_HP1));
    double* C   = (double*)(ws + O_C64);
    float* Hall = ws + O_HALL;

    const int tid = threadIdx.x, bid = blockIdx.x;
    const int w = tid >> 6, lane = tid & 63;
    const int bg = bid >> 6, rg = bid & 63;
    const int bb = (bg << 6) + lane;
    const int r0 = __builtin_amdgcn_readfirstlane((w << 8) + (rg << 2));

    __shared__ double gbuf[4][4][64];

    float4 p = *(const float4*)(problems + ((size_t)bb * SL + t) * 4);
    double a0 = V[r0+0] + (double)p.x*M[r0+0] + (double)p.y*M[1024+r0+0] + (double)p.z*M[2048+r0+0] + (double)p.w*M[3072+r0+0];
    double a1 = V[r0+1] + (double)p.x*M[r0+1] + (double)p.y*M[1024+r0+1] + (double)p.z*M[2048+r0+1] + (double)p.w*M[3072+r0+1];
    double a2 = V[r0+2] + (double)p.x*M[r0+2] + (double)p.y*M[1024+r0+2] + (double)p.z*M[2048+r0+2] + (double)p.w*M[3072+r0+2];
    double a3 = V[r0+3] + (double)p.x*M[r0+3] + (double)p.y*M[1024+r0+3] + (double)p.z*M[2048+r0+3] + (double)p.w*M[3072+r0+3];
    if (t > 0) {
        const double* w0 = Wh + (size_t)(r0+0) * 256;
        const double* w1 = Wh + (size_t)(r0+1) * 256;
        const double* w2 = Wh + (size_t)(r0+2) * 256;
        const double* w3 = Wh + (size_t)(r0+3) * 256;
        const double* hc = Hrd + bb;
#pragma unroll 8
        for (int k = 0; k < 256; ++k) {
            double h = hc[(size_t)k << 9];
            a0 += h * w0[k]; a1 += h * w1[k]; a2 += h * w2[k]; a3 += h * w3[k];
        }
    }
    gbuf[w][0][lane] = a0; gbuf[w][1][lane] = a1;
    gbuf[w][2][lane] = a2; gbuf[w][3][lane] = a3;
    __syncthreads();
    {
        const int j = (rg << 2) + w;  // update thread role: cj = w
        double g0 = gbuf[0][w][lane], g1 = gbuf[1][w][lane];
        double g2 = gbuf[2][w][lane], g3 = gbuf[3][w][lane];
        float ig = sigf((float)g0), fg = sigf((float)g1), gt = tanhf((float)g2), og = sigf((float)g3);
        size_t ci = (size_t)j * 512 + bb;
        double c = (t == 0) ? 0.0 : C[ci];
        c = (double)fg * c + (double)ig * (double)gt;
        C[ci] = c;
        double h = (double)og * (double)tanhf((float)c);
        Hwr[ci] = h;
        Hall[((size_t)bb * SL + t) * 256 + j] = (float)h;
    }
}

// =============== decoder gate step ===============
__global__ __launch_bounds__(256) void gate_dec_k(const float* __restrict__ problems, int t) {
    float* ws = g_ws;
    const double* Wh = (const double*)(ws + O_WHD64);
    const double* M  = (const double*)(ws + O_MD64);
    const double* V  = (const double*)(ws + O_VD64);
    const double* X0 = (const double*)(ws + O_X064);
    const double* Hrd = (const double*)(ws + ((t & 1) ? O_HP1 : O_HP0));
    double* Hwr = (double*)(ws + ((t & 1) ? O_HP0 : O_HP1));
    double* C   = (double*)(ws + O_C64);
    float* Hcur = ws + O_HCUR;
    const int* lastAG = (const int*)(ws + O_LASTA);

    const int tid = threadIdx.x, bid = blockIdx.x;
    const int w = tid >> 6, lane = tid & 63;
    const int bg = bid >> 6, rg = bid & 63;
    const int bb = (bg << 6) + lane;
    const int r0 = __builtin_amdgcn_readfirstlane((w << 8) + (rg << 2));

    __shared__ double gbuf[4][4][64];

    double a0, a1, a2, a3;
    if (t == 0) {
        a0 = X0[r0+0]; a1 = X0[r0+1]; a2 = X0[r0+2]; a3 = X0[r0+3];
    } else {
        int ai = lastAG[bb];
        float4 p = *(const float4*)(problems + ((size_t)bb * SL + ai) * 4);
        a0 = V[r0+0] + (double)p.x*M[r0+0] + (double)p.y*M[1024+r0+0] + (double)p.z*M[2048+r0+0] + (double)p.w*M[3072+r0+0];
        a1 = V[r0+1] + (double)p.x*M[r0+1] + (double)p.y*M[1024+r0+1] + (double)p.z*M[2048+r0+1] + (double)p.w*M[3072+r0+1];
        a2 = V[r0+2] + (double)p.x*M[r0+2] + (double)p.y*M[1024+r0+2] + (double)p.z*M[2048+r0+2] + (double)p.w*M[3072+r0+2];
        a3 = V[r0+3] + (double)p.x*M[r0+3] + (double)p.y*M[1024+r0+3] + (double)p.z*M[2048+r0+3] + (double)p.w*M[3072+r0+3];
    }
    {
        const double* w0 = Wh + (size_t)(r0+0) * 256;
        const double* w1 = Wh + (size_t)(r0+1) * 256;
        const double* w2 = Wh + (size_t)(r0+2) * 256;
        const double* w3 = Wh + (size_t)(r0+3) * 256;
        const double* hc = Hrd + bb;
#pragma unroll 8
        for (int k = 0; k < 256; ++k) {
            double h = hc[(size_t)k << 9];
            a0 += h * w0[k]; a1 += h * w1[k]; a2 += h * w2[k]; a3 += h * w3[k];
        }
    }
    gbuf[w][0][lane] = a0; gbuf[w][1][lane] = a1;
    gbuf[w][2][lane] = a2; gbuf[w][3][lane] = a3;
    __syncthreads();
    {
        const int j = (rg << 2) + w;
        double g0 = gbuf[0][w][lane], g1 = gbuf[1][w][lane];
        double g2 = gbuf[2][w][lane], g3 = gbuf[3][w][lane];
        float ig = sigf((float)g0), fg = sigf((float)g1), gt = tanhf((float)g2), og = sigf((float)g3);
        size_t ci = (size_t)j * 512 + bb;
        double c = C[ci];
        c = (double)fg * c + (double)ig * (double)gt;
        C[ci] = c;
        double h = (double)og * (double)tanhf((float)c);
        Hwr[ci] = h;
        Hcur[(size_t)bb * 256 + j] = (float)h;
    }
}

// =============== refp GEMM: refg/refp[(b,t)][col] = H_all @ WrT + br ===============
// grid (1024, 8), block 256. 64x64 tile, k-tiles of 32.
__global__ __launch_bounds__(256) void refp_gemm(const float* __restrict__ br_g,
                                                 const float* __restrict__ br_p) {
    float* ws = g_ws;
    const float* H = ws + O_HALL;
    const float* W = ws + O_WRT;
    const int bm = blockIdx.x, bn = blockIdx.y;
    const int tid = threadIdx.x;
    const int tr = tid >> 4, tc = tid & 15;
    __shared__ float As[32][65];
    __shared__ float Bs[32][65];
    float acc[4][4] = {};
    for (int kt = 0; kt < 8; ++kt) {
#pragma unroll
        for (int it = 0; it < 8; ++it) {
            int idx = it * 256 + tid;
            int m = idx >> 5, kk = idx & 31;
            As[kk][m] = H[(size_t)(bm * 64 + m) * 256 + kt * 32 + kk];
        }
#pragma unroll
        for (int it = 0; it < 8; ++it) {
            int idx = it * 256 + tid;
            int bk = idx >> 6, bc = idx & 63;
            Bs[bk][bc] = W[(size_t)(kt * 32 + bk) * 512 + bn * 64 + bc];
        }
        __syncthreads();
#pragma unroll
        for (int kk = 0; kk < 32; ++kk) {
            float a0 = As[kk][tr*4+0], a1 = As[kk][tr*4+1], a2 = As[kk][tr*4+2], a3 = As[kk][tr*4+3];
            float b0 = Bs[kk][tc*4+0], b1 = Bs[kk][tc*4+1], b2 = Bs[kk][tc*4+2], b3 = Bs[kk][tc*4+3];
            acc[0][0] = fmaf(a0,b0,acc[0][0]); acc[0][1] = fmaf(a0,b1,acc[0][1]);
            acc[0][2] = fmaf(a0,b2,acc[0][2]); acc[0][3] = fmaf(a0,b3,acc[0][3]);
            acc[1][0] = fmaf(a1,b0,acc[1][0]); acc[1][1] = fmaf(a1,b1,acc[1][1]);
            acc[1][2] = fmaf(a1,b2,acc[1][2]); acc[1][3] = fmaf(a1,b3,acc[1][3]);
            acc[2][0] = fmaf(a2,b0,acc[2][0]); acc[2][1] = fmaf(a2,b1,acc[2][1]);
            acc[2][2] = fmaf(a2,b2,acc[2][2]); acc[2][3] = fmaf(a2,b3,acc[2][3]);
            acc[3][0] = fmaf(a3,b0,acc[3][0]); acc[3][1] = fmaf(a3,b1,acc[3][1]);
            acc[3][2] = fmaf(a3,b2,acc[3][2]); acc[3][3] = fmaf(a3,b3,acc[3][3]);
        }
        __syncthreads();
    }
    const int colg = bn * 64 + tc * 4;
    float4 bias;
    float* outb;
    int colo;
    if (bn < 4) { bias = *(const float4*)(br_g + colg); outb = ws + O_RG; colo = colg; }
    else        { bias = *(const float4*)(br_p + colg - 256); outb = ws + O_RP; colo = colg - 256; }
#pragma unroll
    for (int i = 0; i < 4; ++i) {
        int row = bm * 64 + tr * 4 + i;
        float4 v = make_float4(acc[i][0] + bias.x, acc[i][1] + bias.y,
                               acc[i][2] + bias.z, acc[i][3] + bias.w);
        *(float4*)(outb + (size_t)row * 256 + colo) = v;
    }
}

// =============== decoder attention + sample (one batch per block) ===============
__global__ __launch_bounds__(256) void attn_k(const float* __restrict__ bq_g, const float* __restrict__ Vg,
                                              const float* __restrict__ bq_p, const float* __restrict__ Vp,
                                              float* __restrict__ out, int t) {
    float* ws = g_ws;
    const int b = blockIdx.x, tid = threadIdx.x;
    const int wave = tid >> 6, lane = tid & 63;
    const float* refg = ws + O_RG + (size_t)b * SL * 256;
    const float* refp = ws + O_RP + (size_t)b * SL * 256;
    int* visG = (int*)(ws + O_VIS) + b * SL;
    int* lastAG = (int*)(ws + O_LASTA);

    __shared__ float hb[256];
    __shared__ float qp[256];
    __shared__ float qs[256];
    __shared__ float u_l[128];
    __shared__ float w_l[128];
    __shared__ int visL[128];

    hb[tid] = ws[O_HCUR + (size_t)b * 256 + tid];
    if (tid < 128) visL[tid] = visG[tid];
    __syncthreads();

    {   // qp_g = h @ Wq_g.T + bq_g  (f32, proven class)
        float qa = bq_g[tid];
        const float* Wq = ws + O_WQGT;
#pragma unroll 8
        for (int k = 0; k < 256; ++k) qa = fmaf(hb[k], Wq[(k << 8) + tid], qa);
        qp[tid] = qa;
    }
    __syncthreads();
    {   // glimpse u
        const int d0 = lane, d1 = lane + 64, d2 = lane + 128, d3 = lane + 192;
        const float q0 = qp[d0], q1 = qp[d1], q2 = qp[d2], q3 = qp[d3];
        const float v0 = Vg[d0], v1 = Vg[d1], v2 = Vg[d2], v3 = Vg[d3];
        for (int s = wave; s < SL; s += 4) {
            if (visL[s]) continue;
            const float* r0 = refg + (s << 8);
            float part = tanhf(q0 + r0[d0]) * 10.f * v0;
            part = fmaf(tanhf(q1 + r0[d1]) * 10.f, v1, part);
            part = fmaf(tanhf(q2 + r0[d2]) * 10.f, v2, part);
            part = fmaf(tanhf(q3 + r0[d3]) * 10.f, v3, part);
            for (int off = 32; off; off >>= 1) part += __shfl_xor(part, off, 64);
            if (lane == 0) u_l[s] = part;
        }
    }
    __syncthreads();
    if (wave == 0) {   // glimpse softmax
        int s1 = lane, s2 = lane + 64;
        bool v1 = visL[s1], v2 = visL[s2];
        float m = fmaxf(v1 ? -1e30f : u_l[s1], v2 ? -1e30f : u_l[s2]);
        for (int off = 32; off; off >>= 1) m = fmaxf(m, __shfl_xor(m, off, 64));
        float e1 = v1 ? 0.f : expf(u_l[s1] - m);
        float e2 = v2 ? 0.f : expf(u_l[s2] - m);
        float den = e1 + e2;
        for (int off = 32; off; off >>= 1) den += __shfl_xor(den, off, 64);
        w_l[s1] = e1 / den;
        w_l[s2] = e2 / den;
    }
    __syncthreads();
    {   // q = sum_s w[s] * refg[s,:]
        float q = 0.f;
        for (int s = 0; s < SL; ++s)
            if (!visL[s]) q = fmaf(w_l[s], refg[(s << 8) + tid], q);
        qs[tid] = q;
    }
    __syncthreads();
    {   // qp_p = q @ Wq_p.T + bq_p
        float qa = bq_p[tid];
        const float* Wq = ws + O_WQPT;
#pragma unroll 8
        for (int k = 0; k < 256; ++k) qa = fmaf(qs[k], Wq[(k << 8) + tid], qa);
        qp[tid] = qa;
    }
    __syncthreads();
    {   // pointer logits
        const int d0 = lane, d1 = lane + 64, d2 = lane + 128, d3 = lane + 192;
        const float q0 = qp[d0], q1 = qp[d1], q2 = qp[d2], q3 = qp[d3];
        const float v0 = Vp[d0], v1 = Vp[d1], v2 = Vp[d2], v3 = Vp[d3];
        for (int s = wave; s < SL; s += 4) {
            if (visL[s]) continue;
            const float* r0 = refp + (s << 8);
            float part = tanhf(q0 + r0[d0]) * 10.f * v0;
            part = fmaf(tanhf(q1 + r0[d1]) * 10.f, v1, part);
            part = fmaf(tanhf(q2 + r0[d2]) * 10.f, v2, part);
            part = fmaf(tanhf(q3 + r0[d3]) * 10.f, v3, part);
            for (int off = 32; off; off >>= 1) part += __shfl_xor(part, off, 64);
            if (lane == 0) u_l[s] = part;
        }
    }
    __syncthreads();
    if (wave == 0) {   // sample (jax-exact gumbel argmax)
        int s1 = lane, s2 = lane + 64;
        bool v1 = visL[s1], v2 = visL[s2];
        float m = fmaxf(v1 ? -1e30f : u_l[s1], v2 ? -1e30f : u_l[s2]);
        for (int off = 32; off; off >>= 1) m = fmaxf(m, __shfl_xor(m, off, 64));
        float e1 = v1 ? 0.f : expf(u_l[s1] - m);
        float e2 = v2 ? 0.f : expf(u_l[s2] - m);
        float den = e1 + e2;
        for (int off = 32; off; off >>= 1) den += __shfl_xor(den, off, 64);
        uint32_t kk0, kk1;
        tf2x32(0u, 1u, 0u, (uint32_t)t, kk0, kk1);
        double z1 = v1 ? -1.0e300 : (double)u_l[s1] + gumbel_jax(kk0, kk1, (uint32_t)(b * 128 + s1));
        double z2 = v2 ? -1.0e300 : (double)u_l[s2] + gumbel_jax(kk0, kk1, (uint32_t)(b * 128 + s2));
        double bz; int bi;
        if (z2 > z1) { bz = z2; bi = s2; } else { bz = z1; bi = s1; }
        for (int off = 32; off; off >>= 1) {
            double oz = __shfl_xor(bz, off, 64);
            int oi = __shfl_xor(bi, off, 64);
            if (oz > bz || (oz == bz && oi < bi)) { bz = oz; bi = oi; }
        }
        if (lane == 0) {
            float pr = expf(u_l[bi] - m) / den;
            out[t * NB + b] = pr;
            out[SL * NB + t * NB + b] = (float)bi;
            visG[bi] = 1;
            lastAG[b] = bi;
        }
    }
}

extern "C" void kernel_launch(void* const* d_in, const int* in_sizes, int n_in,
                              void* d_out, int out_size, void* d_ws, size_t ws_size,
                              hipStream_t stream) {
    (void)d_ws; (void)ws_size; (void)n_in; (void)in_sizes; (void)out_size;
    const float* problems = (const float*)d_in[0];
    const float* embed_W  = (const float*)d_in[1];
    const float* embed_b  = (const float*)d_in[2];
    const float* Wi_enc   = (const float*)d_in[3];
    const float* Wh_enc   = (const float*)d_in[4];
    const float* b_enc    = (const float*)d_in[5];
    const float* Wi_dec   = (const float*)d_in[6];
    const float* Wh_dec   = (const float*)d_in[7];
    const float* b_dec    = (const float*)d_in[8];
    const float* dec0     = (const float*)d_in[9];
    const float* Wq_g     = (const float*)d_in[10];
    const float* bq_g     = (const float*)d_in[11];
    const float* Wr_g     = (const float*)d_in[12];
    const float* br_g     = (const float*)d_in[13];
    const float* V_g      = (const float*)d_in[14];
    const float* Wq_p     = (const float*)d_in[15];
    const float* bq_p     = (const float*)d_in[16];
    const float* Wr_p     = (const float*)d_in[17];
    const float* br_p     = (const float*)d_in[18];
    const float* V_p      = (const float*)d_in[19];
    float* outp = (float*)d_out;

    hipLaunchKernelGGL(pre_k, dim3(512), dim3(256), 0, stream,
                       embed_W, embed_b, Wi_enc, Wh_enc, b_enc,
                       Wi_dec, Wh_dec, b_dec, dec0, Wr_g, Wr_p, Wq_g, Wq_p);

    for (int t = 0; t < SL; ++t)
        hipLaunchKernelGGL(gate_enc_k, dim3(512), dim3(256), 0, stream, problems, t);

    hipLaunchKernelGGL(refp_gemm, dim3(1024, 8), dim3(256), 0, stream, br_g, br_p);

    for (int t = 0; t < SL; ++t) {
        hipLaunchKernelGGL(gate_dec_k, dim3(512), dim3(256), 0, stream, problems, t);
        hipLaunchKernelGGL(attn_k, dim3(512), dim3(256), 0, stream, bq_g, V_g, bq_p, V_p, outp, t);
    }
}